// Round 5
// baseline (121.805 us; speedup 1.0000x reference)
//
#include <hip/hip_runtime.h>

// EdgeCompute v5: direct per-lane B-fragment gather from f16 x, zero LDS,
// zero spill.  out = sigmoid( relu(|x[s]-x[d]| @ W1 + b1) @ W2 + b2 )
// N_EDGES=640000, D_FEAT=128, HID=64.
//
// Round-4 lesson: WRITE_SIZE 29MB = scratch spills from the 64-int id
// pipeline arrays. Fix: per-lane id loads (2 VGPRs), and exploit that f16
// rows make the per-lane gather line-perfect IN B-FRAGMENT LAYOUT:
// lane(edge=L&15, q=L>>4) half8-loads row*256B + kb*64 + q*16 -> the 4 quads
// of an edge consume exactly one 64B line; 16 fully-used lines/instr (same
// line count as coalesced) with NO LDS / shfl / transpose.
// A = W1^T in 64 VGPRs from pre-transposed f16 w1t (d_ws). D[hid][edge].
// Pipeline: rows 1 group ahead, ids 2 groups ahead. No barriers.

#define DF 128
#define HID 64

typedef _Float16 half8   __attribute__((ext_vector_type(8)));
typedef _Float16 half4_t __attribute__((ext_vector_type(4)));
typedef float    floatx4 __attribute__((ext_vector_type(4)));

__device__ __forceinline__ float sigmoidf_(float t) {
    return __builtin_amdgcn_rcpf(1.0f + __expf(-t));
}

// pre-pass: x -> f16 (L2-resident 2.56MB), W1 -> f16 transposed [hid][feat]
__global__ void cvt_pre(const float* __restrict__ x, const float* __restrict__ W1,
                        _Float16* __restrict__ xh, _Float16* __restrict__ w1t, int n4)
{
    const int i = blockIdx.x * blockDim.x + threadIdx.x;
    if (i < n4) {
        float4 v = ((const float4*)x)[i];
        half4_t h = { (_Float16)v.x, (_Float16)v.y, (_Float16)v.z, (_Float16)v.w };
        ((half4_t*)xh)[i] = h;
    }
    if (i < DF * HID) {                      // w1t[h*128+f] = W1[f*64+h]
        const int h = i >> 7, f = i & 127;
        w1t[i] = (_Float16)W1[f * HID + h];
    }
}

__global__ __launch_bounds__(256, 3) void edge_mlp_v5(
    const _Float16* __restrict__ xh, const _Float16* __restrict__ w1t,
    const int* __restrict__ idx,
    const float* __restrict__ b1, const float* __restrict__ W2,
    const float* __restrict__ b2,
    float* __restrict__ out, int n_edges, int ngroups, int gstride)
{
    const int tid = threadIdx.x;
    const int L   = tid & 63;
    const int r16 = L & 15;            // edge within wave tile / A-row m
    const int q   = L >> 4;            // quad: k = q*8+j
    const int wv  = tid >> 6;          // wave in block

    // ---- A fragments: W1^T [hid=mt*16+r16][feat=kb*32+q*8+j] ----
    half8 wf[4][4];
#pragma unroll
    for (int mt = 0; mt < 4; ++mt)
#pragma unroll
        for (int kb = 0; kb < 4; ++kb)
            wf[mt][kb] = *(const half8*)(w1t + (size_t)(mt * 16 + r16) * DF + kb * 32 + q * 8);

    // epilogue constants at hid = mt*16 + q*4 + r (f16-packed: 8 VGPRs total)
    half4_t b1h[4], w2h[4];
#pragma unroll
    for (int mt = 0; mt < 4; ++mt)
#pragma unroll
        for (int r = 0; r < 4; ++r) {
            b1h[mt][r] = (_Float16)b1[mt * 16 + q * 4 + r];
            w2h[mt][r] = (_Float16)W2[mt * 16 + q * 4 + r];
        }
    const float b2v = b2[0];

    const int g0 = blockIdx.x;

    // ---- pipeline preamble: ids(g0) -> rows(g0); ids(g0+gs) ----
    int sid, did;
    {
        int e0 = g0 * 64 + wv * 16 + r16;
        if (e0 >= n_edges) e0 = n_edges - 1;
        sid = idx[e0]; did = idx[n_edges + e0];
    }
    half8 rs[4], rd[4];
#pragma unroll
    for (int kb = 0; kb < 4; ++kb) {
        rs[kb] = *(const half8*)(xh + (size_t)sid * DF + kb * 32 + q * 8);
        rd[kb] = *(const half8*)(xh + (size_t)did * DF + kb * 32 + q * 8);
    }
    {
        int g1 = g0 + gstride; if (g1 >= ngroups) g1 = g0;
        int e1 = g1 * 64 + wv * 16 + r16; if (e1 >= n_edges) e1 = n_edges - 1;
        sid = idx[e1]; did = idx[n_edges + e1];
    }

    // ---- main loop: no LDS, no barriers ----
#pragma unroll 1
    for (int g = g0; g < ngroups; g += gstride) {
        // B fragments = |rs - rd| (f16 packed sub + abs-mask)
        half8 bf[4];
#pragma unroll
        for (int kb = 0; kb < 4; ++kb) {
            union { half8 h; uint4 u; } U;
            U.h = rs[kb] - rd[kb];
            U.u.x &= 0x7FFF7FFFu; U.u.y &= 0x7FFF7FFFu;
            U.u.z &= 0x7FFF7FFFu; U.u.w &= 0x7FFF7FFFu;
            bf[kb] = U.h;
        }

        // issue next group's row loads (ids prefetched last iter)
#pragma unroll
        for (int kb = 0; kb < 4; ++kb) {
            rs[kb] = *(const half8*)(xh + (size_t)sid * DF + kb * 32 + q * 8);
            rd[kb] = *(const half8*)(xh + (size_t)did * DF + kb * 32 + q * 8);
        }

        // prefetch ids for g + 2*gstride (2 dword loads, 1 line)
        {
            int g2 = g + 2 * gstride; if (g2 >= ngroups) g2 = g;
            int e2 = g2 * 64 + wv * 16 + r16; if (e2 >= n_edges) e2 = n_edges - 1;
            sid = idx[e2]; did = idx[n_edges + e2];
        }

        // MFMA: D[hid][edge] = W1^T * diff  (acc init = b1)
        floatx4 acc[4];
#pragma unroll
        for (int mt = 0; mt < 4; ++mt)
#pragma unroll
            for (int r = 0; r < 4; ++r)
                acc[mt][r] = (float)b1h[mt][r];
#pragma unroll
        for (int kb = 0; kb < 4; ++kb)
#pragma unroll
            for (int mt = 0; mt < 4; ++mt)
                acc[mt] = __builtin_amdgcn_mfma_f32_16x16x32_f16(wf[mt][kb], bf[kb], acc[mt], 0, 0, 0);

        // epilogue: relu -> *W2 -> reduce over q (2 shfl) -> sigmoid -> store
        float part = 0.f;
#pragma unroll
        for (int mt = 0; mt < 4; ++mt)
#pragma unroll
            for (int r = 0; r < 4; ++r)
                part = fmaf(fmaxf(acc[mt][r], 0.f), (float)w2h[mt][r], part);
        part += __shfl_xor(part, 16, 64);
        part += __shfl_xor(part, 32, 64);
        if (L < 16) {
            const int e = g * 64 + wv * 16 + L;
            if (e < n_edges) out[e] = sigmoidf_(part + b2v);
        }
    }
}

// fallback (ws too small) / tail: naive per-edge
__global__ void edge_naive(const float* __restrict__ x, const int* __restrict__ idx,
                           const float* __restrict__ W1, const float* __restrict__ b1,
                           const float* __restrict__ W2, const float* __restrict__ b2,
                           float* __restrict__ out, int n_edges, int start)
{
    int e = start + blockIdx.x * blockDim.x + threadIdx.x;
    if (e >= n_edges) return;
    int s = idx[e], d = idx[n_edges + e];
    float t = b2[0];
    for (int j = 0; j < HID; ++j) {
        float h = b1[j];
        for (int k = 0; k < DF; ++k)
            h = fmaf(fabsf(x[(size_t)s * DF + k] - x[(size_t)d * DF + k]), W1[(size_t)k * HID + j], h);
        t = fmaf(fmaxf(h, 0.f), W2[j], t);
    }
    out[e] = sigmoidf_(t);
}

extern "C" void kernel_launch(void* const* d_in, const int* in_sizes, int n_in,
                              void* d_out, int out_size, void* d_ws, size_t ws_size,
                              hipStream_t stream) {
    const float* x   = (const float*)d_in[0];
    const int*   idx = (const int*)d_in[1];
    const float* W1  = (const float*)d_in[2];
    const float* b1  = (const float*)d_in[3];
    const float* W2  = (const float*)d_in[4];
    const float* b2  = (const float*)d_in[5];
    float* out = (float*)d_out;

    const int n_edges = in_sizes[1] / 2;      // indices is [2, n_edges]
    const int n_x     = in_sizes[0];
    const int ngroups = n_edges / 64;
    const int rem     = n_edges - ngroups * 64;

    const size_t xh_bytes  = ((size_t)n_x * sizeof(_Float16) + 255) & ~(size_t)255;
    const size_t w1t_bytes = (size_t)DF * HID * sizeof(_Float16);
    const bool ok = (ws_size >= xh_bytes + w1t_bytes) && (n_x % 4 == 0);

    if (ok && ngroups > 0) {
        _Float16* xh  = (_Float16*)d_ws;
        _Float16* w1t = (_Float16*)((char*)d_ws + xh_bytes);
        const int n4 = n_x / 4;
        cvt_pre<<<(n4 + 255) / 256, 256, 0, stream>>>(x, W1, xh, w1t, n4);

        const int grid = ngroups < 1280 ? ngroups : 1280;
        edge_mlp_v5<<<grid, 256, 0, stream>>>(xh, w1t, idx, b1, W2, b2,
                                              out, n_edges, ngroups, grid);
        if (rem > 0)
            edge_naive<<<(rem + 63) / 64, 64, 0, stream>>>(x, idx, W1, b1, W2, b2,
                                                           out, n_edges, ngroups * 64);
    } else {
        edge_naive<<<(n_edges + 63) / 64, 64, 0, stream>>>(x, idx, W1, b1, W2, b2,
                                                           out, n_edges, 0);
    }
}

// Round 6
// 102.001 us; speedup vs baseline: 1.1942x; 1.1942x over previous
//
#include <hip/hip_runtime.h>

// EdgeCompute v6: lane-contiguous row gather + per-wave LDS transpose + no spill.
//   out = sigmoid( relu(|x[s]-x[d]| @ W1 + b1) @ W2 + b2 )
// N_EDGES=640000, D_FEAT=128, HID=64.
//
// Round-5 lesson: scattered per-lane gather (16 discontiguous rows/instr) is
// TA-serialized even at identical cacheline counts -> lane-CONTIGUOUS loads
// only (one instr = 4 whole 256B f16 rows, consecutive lanes). Transpose to
// MFMA B-fragment layout via per-wave LDS (no barriers). Round-4 lesson: no
// lambdas / pointer-passed arrays (scratch spills); ids flow through s_load
// -> 3x v_cndmask per row (8 VGPRs/stage). A = W1^T in 64 VGPRs (pre-
// transposed f16 w1t in d_ws). D[hid][edge]; epilogue reduce = 2 shfl_xor.

#define DF 128
#define HID 64
#define AST 136   // halfs per LDS diff row (272 B): 4 rows cover banks evenly

typedef _Float16 half8   __attribute__((ext_vector_type(8)));
typedef _Float16 half4_t __attribute__((ext_vector_type(4)));
typedef float    floatx4 __attribute__((ext_vector_type(4)));

__device__ __forceinline__ float sigmoidf_(float t) {
    return __builtin_amdgcn_rcpf(1.0f + __expf(-t));
}

// pre-pass: x -> f16 (2.56MB, L2-resident), W1 -> f16 transposed [hid][feat]
__global__ void cvt_pre(const float* __restrict__ x, const float* __restrict__ W1,
                        _Float16* __restrict__ xh, _Float16* __restrict__ w1t, int n4)
{
    const int i = blockIdx.x * blockDim.x + threadIdx.x;
    if (i < n4) {
        float4 v = ((const float4*)x)[i];
        half4_t h = { (_Float16)v.x, (_Float16)v.y, (_Float16)v.z, (_Float16)v.w };
        ((half4_t*)xh)[i] = h;
    }
    if (i < DF * HID) {                      // w1t[h*128+f] = W1[f*64+h]
        const int h = i >> 7, f = i & 127;
        w1t[i] = (_Float16)W1[f * HID + h];
    }
}

__global__ __launch_bounds__(256, 3) void edge_mlp_v6(
    const _Float16* __restrict__ xh, const _Float16* __restrict__ w1t,
    const int* __restrict__ idx,
    const float* __restrict__ b1, const float* __restrict__ W2,
    const float* __restrict__ b2,
    float* __restrict__ out, int n_edges, int ngroups, int gstride)
{
    // per-wave diff tile: [m=16 edges][k=128 (+8 pad)] f16
    __shared__ __attribute__((aligned(16))) _Float16 lds_d[4][16 * AST];

    const int tid = threadIdx.x;
    const int L   = tid & 63;
    const int r16 = L & 15;                 // frag-read: edge; gather: 16B chunk
    const int q   = L >> 4;                 // frag-read: quad; gather: row-in-quartet
    const int wv  = __builtin_amdgcn_readfirstlane(tid) >> 6;
    _Float16* const ldsw = &lds_d[wv][0];

    // ---- A fragments: W1^T [hid=mt*16+r16][feat=kb*32+q*8+j] (64 VGPRs) ----
    half8 wf[4][4];
#pragma unroll
    for (int mt = 0; mt < 4; ++mt)
#pragma unroll
        for (int kb = 0; kb < 4; ++kb)
            wf[mt][kb] = *(const half8*)(w1t + (size_t)(mt * 16 + r16) * DF + kb * 32 + q * 8);

    // epilogue constants at hid = mt*16 + q*4 + r (f16-packed)
    half4_t b1h[4], w2h[4];
#pragma unroll
    for (int mt = 0; mt < 4; ++mt)
#pragma unroll
        for (int r = 0; r < 4; ++r) {
            b1h[mt][r] = (_Float16)b1[mt * 16 + q * 4 + r];
            w2h[mt][r] = (_Float16)W2[mt * 16 + q * 4 + r];
        }
    const float b2v = b2[0];

    // per-lane fixed offsets
    const int goff   = r16 * 8;              // halfs into a row for the gather
    const int wbase  = q * AST + r16 * 8;    // LDS write vaddr (halfs); +p*4*AST imm
    const int rbase  = r16 * AST + q * 8;    // LDS frag-read vaddr; +kb*32 imm

    // id select: this lane gathers row (4p + q) of the group -> 3 cndmask
#define SEL4(a0, a1, a2, a3) ((q & 2) ? ((q & 1) ? (a3) : (a2)) : ((q & 1) ? (a1) : (a0)))

    const int g0 = blockIdx.x;

    // selected ids for the group whose ROWS we issue next (8 VGPRs)
    int sA0, sA1, sA2, sA3, dA0, dA1, dA2, dA3;
    {
        const int ebu = __builtin_amdgcn_readfirstlane(g0 * 64 + wv * 16);
        const int* __restrict__ ip = idx + ebu;
        const int* __restrict__ jp = idx + n_edges + ebu;
        sA0 = SEL4(ip[0], ip[1], ip[2], ip[3]);
        sA1 = SEL4(ip[4], ip[5], ip[6], ip[7]);
        sA2 = SEL4(ip[8], ip[9], ip[10], ip[11]);
        sA3 = SEL4(ip[12], ip[13], ip[14], ip[15]);
        dA0 = SEL4(jp[0], jp[1], jp[2], jp[3]);
        dA1 = SEL4(jp[4], jp[5], jp[6], jp[7]);
        dA2 = SEL4(jp[8], jp[9], jp[10], jp[11]);
        dA3 = SEL4(jp[12], jp[13], jp[14], jp[15]);
    }

    // ---- preamble: fill LDS for g0 ----
    {
        half8 rs[4], rd[4];
        rs[0] = *(const half8*)(xh + (size_t)sA0 * DF + goff);
        rs[1] = *(const half8*)(xh + (size_t)sA1 * DF + goff);
        rs[2] = *(const half8*)(xh + (size_t)sA2 * DF + goff);
        rs[3] = *(const half8*)(xh + (size_t)sA3 * DF + goff);
        rd[0] = *(const half8*)(xh + (size_t)dA0 * DF + goff);
        rd[1] = *(const half8*)(xh + (size_t)dA1 * DF + goff);
        rd[2] = *(const half8*)(xh + (size_t)dA2 * DF + goff);
        rd[3] = *(const half8*)(xh + (size_t)dA3 * DF + goff);
#pragma unroll
        for (int p = 0; p < 4; ++p) {
            union { half8 h; uint4 u; } U;
            U.h = rs[p] - rd[p];
            U.u.x &= 0x7FFF7FFFu; U.u.y &= 0x7FFF7FFFu;
            U.u.z &= 0x7FFF7FFFu; U.u.w &= 0x7FFF7FFFu;
            *(half8*)(ldsw + wbase + p * 4 * AST) = U.h;
        }
    }

    // ids for g0 + gstride
    {
        int g1 = g0 + gstride; if (g1 >= ngroups) g1 = g0;
        const int ebu = __builtin_amdgcn_readfirstlane(g1 * 64 + wv * 16);
        const int* __restrict__ ip = idx + ebu;
        const int* __restrict__ jp = idx + n_edges + ebu;
        sA0 = SEL4(ip[0], ip[1], ip[2], ip[3]);
        sA1 = SEL4(ip[4], ip[5], ip[6], ip[7]);
        sA2 = SEL4(ip[8], ip[9], ip[10], ip[11]);
        sA3 = SEL4(ip[12], ip[13], ip[14], ip[15]);
        dA0 = SEL4(jp[0], jp[1], jp[2], jp[3]);
        dA1 = SEL4(jp[4], jp[5], jp[6], jp[7]);
        dA2 = SEL4(jp[8], jp[9], jp[10], jp[11]);
        dA3 = SEL4(jp[12], jp[13], jp[14], jp[15]);
    }

    // ---- main loop: no barriers (per-wave LDS, DS ops are in-order) ----
#pragma unroll 1
    for (int g = g0; g < ngroups; g += gstride) {
        // 1) issue lane-contiguous row loads for g+1 (4 whole rows per instr)
        half8 rs[4], rd[4];
        rs[0] = *(const half8*)(xh + (size_t)sA0 * DF + goff);
        rs[1] = *(const half8*)(xh + (size_t)sA1 * DF + goff);
        rs[2] = *(const half8*)(xh + (size_t)sA2 * DF + goff);
        rs[3] = *(const half8*)(xh + (size_t)sA3 * DF + goff);
        rd[0] = *(const half8*)(xh + (size_t)dA0 * DF + goff);
        rd[1] = *(const half8*)(xh + (size_t)dA1 * DF + goff);
        rd[2] = *(const half8*)(xh + (size_t)dA2 * DF + goff);
        rd[3] = *(const half8*)(xh + (size_t)dA3 * DF + goff);

        // 2) ids for g + 2*gstride (s_load + 3 cndmask each; lands next iter)
        int sN0, sN1, sN2, sN3, dN0, dN1, dN2, dN3;
        {
            int g2 = g + 2 * gstride; if (g2 >= ngroups) g2 = g;
            const int ebu = __builtin_amdgcn_readfirstlane(g2 * 64 + wv * 16);
            const int* __restrict__ ip = idx + ebu;
            const int* __restrict__ jp = idx + n_edges + ebu;
            sN0 = SEL4(ip[0], ip[1], ip[2], ip[3]);
            sN1 = SEL4(ip[4], ip[5], ip[6], ip[7]);
            sN2 = SEL4(ip[8], ip[9], ip[10], ip[11]);
            sN3 = SEL4(ip[12], ip[13], ip[14], ip[15]);
            dN0 = SEL4(jp[0], jp[1], jp[2], jp[3]);
            dN1 = SEL4(jp[4], jp[5], jp[6], jp[7]);
            dN2 = SEL4(jp[8], jp[9], jp[10], jp[11]);
            dN3 = SEL4(jp[12], jp[13], jp[14], jp[15]);
        }

        // 3) MFMA on LDS tile (group g): D[hid][edge] = W1^T * diff, acc=b1
        floatx4 acc[4];
#pragma unroll
        for (int mt = 0; mt < 4; ++mt)
#pragma unroll
            for (int r = 0; r < 4; ++r)
                acc[mt][r] = (float)b1h[mt][r];
#pragma unroll
        for (int kb = 0; kb < 4; ++kb) {
            const half8 bf = *(const half8*)(ldsw + rbase + kb * 32);
#pragma unroll
            for (int mt = 0; mt < 4; ++mt)
                acc[mt] = __builtin_amdgcn_mfma_f32_16x16x32_f16(wf[mt][kb], bf, acc[mt], 0, 0, 0);
        }

        // 4) epilogue: relu -> *W2 -> reduce over q -> sigmoid -> store
        float part = 0.f;
#pragma unroll
        for (int mt = 0; mt < 4; ++mt)
#pragma unroll
            for (int r = 0; r < 4; ++r)
                part = fmaf(fmaxf(acc[mt][r], 0.f), (float)w2h[mt][r], part);
        part += __shfl_xor(part, 16, 64);
        part += __shfl_xor(part, 32, 64);
        if (L < 16) {
            const int e = g * 64 + wv * 16 + L;
            if (e < n_edges) out[e] = sigmoidf_(part + b2v);
        }

        // 5) diff (g+1) -> LDS (after this iter's frag reads; in-order DS)
#pragma unroll
        for (int p = 0; p < 4; ++p) {
            union { half8 h; uint4 u; } U;
            U.h = rs[p] - rd[p];
            U.u.x &= 0x7FFF7FFFu; U.u.y &= 0x7FFF7FFFu;
            U.u.z &= 0x7FFF7FFFu; U.u.w &= 0x7FFF7FFFu;
            *(half8*)(ldsw + wbase + p * 4 * AST) = U.h;
        }

        // 6) advance id pipeline
        sA0 = sN0; sA1 = sN1; sA2 = sN2; sA3 = sN3;
        dA0 = dN0; dA1 = dN1; dA2 = dN2; dA3 = dN3;
    }
#undef SEL4
}

// fallback / tail
__global__ void edge_naive(const float* __restrict__ x, const int* __restrict__ idx,
                           const float* __restrict__ W1, const float* __restrict__ b1,
                           const float* __restrict__ W2, const float* __restrict__ b2,
                           float* __restrict__ out, int n_edges, int start)
{
    int e = start + blockIdx.x * blockDim.x + threadIdx.x;
    if (e >= n_edges) return;
    int s = idx[e], d = idx[n_edges + e];
    float t = b2[0];
    for (int j = 0; j < HID; ++j) {
        float h = b1[j];
        for (int k = 0; k < DF; ++k)
            h = fmaf(fabsf(x[(size_t)s * DF + k] - x[(size_t)d * DF + k]), W1[(size_t)k * HID + j], h);
        t = fmaf(fmaxf(h, 0.f), W2[j], t);
    }
    out[e] = sigmoidf_(t);
}

extern "C" void kernel_launch(void* const* d_in, const int* in_sizes, int n_in,
                              void* d_out, int out_size, void* d_ws, size_t ws_size,
                              hipStream_t stream) {
    const float* x   = (const float*)d_in[0];
    const int*   idx = (const int*)d_in[1];
    const float* W1  = (const float*)d_in[2];
    const float* b1  = (const float*)d_in[3];
    const float* W2  = (const float*)d_in[4];
    const float* b2  = (const float*)d_in[5];
    float* out = (float*)d_out;

    const int n_edges = in_sizes[1] / 2;      // indices is [2, n_edges]
    const int n_x     = in_sizes[0];
    const int ngroups = n_edges / 64;
    const int rem     = n_edges - ngroups * 64;

    const size_t xh_bytes  = ((size_t)n_x * sizeof(_Float16) + 255) & ~(size_t)255;
    const size_t w1t_bytes = (size_t)DF * HID * sizeof(_Float16);
    const bool ok = (ws_size >= xh_bytes + w1t_bytes) && (n_x % 4 == 0);

    if (ok && ngroups > 0) {
        _Float16* xh  = (_Float16*)d_ws;
        _Float16* w1t = (_Float16*)((char*)d_ws + xh_bytes);
        const int n4 = n_x / 4;
        cvt_pre<<<(n4 + 255) / 256, 256, 0, stream>>>(x, W1, xh, w1t, n4);

        const int grid = ngroups < 768 ? ngroups : 768;   // 3 blocks/CU
        edge_mlp_v6<<<grid, 256, 0, stream>>>(xh, w1t, idx, b1, W2, b2,
                                              out, n_edges, ngroups, grid);
        if (rem > 0)
            edge_naive<<<(rem + 63) / 64, 64, 0, stream>>>(x, idx, W1, b1, W2, b2,
                                                           out, n_edges, ngroups * 64);
    } else {
        edge_naive<<<(n_edges + 63) / 64, 64, 0, stream>>>(x, idx, W1, b1, W2, b2,
                                                           out, n_edges, 0);
    }
}

// Round 7
// 97.946 us; speedup vs baseline: 1.2436x; 1.0414x over previous
//
#include <hip/hip_runtime.h>

// EdgeCompute v7: v6 minus SMEM-in-loop (lgkm contamination fix).
//   out = sigmoid( relu(|x[s]-x[d]| @ W1 + b1) @ W2 + b2 )
// N_EDGES=640000, D_FEAT=128, HID=64.
//
// Round-6 lesson: uniform id reads became s_load (SMEM). SMEM shares lgkmcnt
// with DS and completes out-of-order, so the compiler drains lgkmcnt(0)
// before each ds_read -> every iteration eats an SMEM round-trip (~300cyc).
// Fix: rows assigned q*4+p so each lane's 4 ids are CONTIGUOUS -> one
// global_load_dwordx4 (VMEM) per endpoint per iter. Loop lgkm = DS only.
// Kept from v6: lane-contiguous row gather (one instr = 4 whole 256B f16
// rows), per-wave LDS transpose (no barriers), W1^T in 64 VGPRs, transposed
// MFMA D[hid][edge], 2-swizzle epilogue, ids 2 groups ahead, rows 1 ahead.

#define DF 128
#define HID 64
#define AST 136   // halfs per LDS diff row (272 B = 17*16B, 16B-aligned rows)

typedef _Float16 half8   __attribute__((ext_vector_type(8)));
typedef _Float16 half4_t __attribute__((ext_vector_type(4)));
typedef float    floatx4 __attribute__((ext_vector_type(4)));

__device__ __forceinline__ float sigmoidf_(float t) {
    return __builtin_amdgcn_rcpf(1.0f + __expf(-t));
}

// pre-pass: x -> f16 (2.56MB, L2-resident), W1 -> f16 transposed [hid][feat]
__global__ void cvt_pre(const float* __restrict__ x, const float* __restrict__ W1,
                        _Float16* __restrict__ xh, _Float16* __restrict__ w1t, int n4)
{
    const int i = blockIdx.x * blockDim.x + threadIdx.x;
    if (i < n4) {
        float4 v = ((const float4*)x)[i];
        half4_t h = { (_Float16)v.x, (_Float16)v.y, (_Float16)v.z, (_Float16)v.w };
        ((half4_t*)xh)[i] = h;
    }
    if (i < DF * HID) {                      // w1t[h*128+f] = W1[f*64+h]
        const int h = i >> 7, f = i & 127;
        w1t[i] = (_Float16)W1[f * HID + h];
    }
}

__global__ __launch_bounds__(256, 3) void edge_mlp_v7(
    const _Float16* __restrict__ xh, const _Float16* __restrict__ w1t,
    const int* __restrict__ idx,
    const float* __restrict__ b1, const float* __restrict__ W2,
    const float* __restrict__ b2,
    float* __restrict__ out, int n_edges, int ngroups, int gstride)
{
    // per-wave diff tile: [m=16 edges][k=128 (+8 pad)] f16
    __shared__ __attribute__((aligned(16))) _Float16 lds_d[4][16 * AST];

    const int tid = threadIdx.x;
    const int L   = tid & 63;
    const int r16 = L & 15;                 // frag-read: edge; gather: 16B chunk
    const int q   = L >> 4;                 // frag-read: quad; gather: row quartet
    const int wv  = tid >> 6;
    _Float16* const ldsw = &lds_d[wv][0];

    // ---- A fragments: W1^T [hid=mt*16+r16][feat=kb*32+q*8+j] ----
    half8 wf[4][4];
#pragma unroll
    for (int mt = 0; mt < 4; ++mt)
#pragma unroll
        for (int kb = 0; kb < 4; ++kb)
            wf[mt][kb] = *(const half8*)(w1t + (size_t)(mt * 16 + r16) * DF + kb * 32 + q * 8);

    // epilogue constants at hid = mt*16 + q*4 + r (f16-packed, 8 VGPRs)
    half4_t b1h[4], w2h[4];
#pragma unroll
    for (int mt = 0; mt < 4; ++mt)
#pragma unroll
        for (int r = 0; r < 4; ++r) {
            b1h[mt][r] = (_Float16)b1[mt * 16 + q * 4 + r];
            w2h[mt][r] = (_Float16)W2[mt * 16 + q * 4 + r];
        }
    const float b2v = b2[0];

    // per-lane fixed offsets
    const int goff  = r16 * 8;               // halfs into a row for the gather
    const int wbase = q * 4 * AST + r16 * 8; // LDS write vaddr; +p*AST imm
    const int rbase = r16 * AST + q * 8;     // LDS frag-read vaddr; +kb*32 imm
    const int idoff = q * 4;                 // this lane's 4 contiguous ids

    const int g0 = blockIdx.x;

    // ids for the group whose ROWS we issue next (VMEM dwordx4, 1 line/wave)
    int4 sI, dI;
    {
        const int eb = g0 * 64 + wv * 16;
        sI = *(const int4*)(idx + eb + idoff);
        dI = *(const int4*)(idx + n_edges + eb + idoff);
    }

    // ---- preamble: rows(g0) -> diff -> LDS ----
    {
        half8 rs[4], rd[4];
        rs[0] = *(const half8*)(xh + (size_t)sI.x * DF + goff);
        rs[1] = *(const half8*)(xh + (size_t)sI.y * DF + goff);
        rs[2] = *(const half8*)(xh + (size_t)sI.z * DF + goff);
        rs[3] = *(const half8*)(xh + (size_t)sI.w * DF + goff);
        rd[0] = *(const half8*)(xh + (size_t)dI.x * DF + goff);
        rd[1] = *(const half8*)(xh + (size_t)dI.y * DF + goff);
        rd[2] = *(const half8*)(xh + (size_t)dI.z * DF + goff);
        rd[3] = *(const half8*)(xh + (size_t)dI.w * DF + goff);
#pragma unroll
        for (int p = 0; p < 4; ++p) {
            union { half8 h; uint4 u; } U;
            U.h = rs[p] - rd[p];
            U.u.x &= 0x7FFF7FFFu; U.u.y &= 0x7FFF7FFFu;
            U.u.z &= 0x7FFF7FFFu; U.u.w &= 0x7FFF7FFFu;
            *(half8*)(ldsw + wbase + p * AST) = U.h;
        }
    }

    // ids for g0 + gstride
    {
        int g1 = g0 + gstride; if (g1 >= ngroups) g1 = g0;
        const int eb = g1 * 64 + wv * 16;
        sI = *(const int4*)(idx + eb + idoff);
        dI = *(const int4*)(idx + n_edges + eb + idoff);
    }

    // ---- main loop: DS-only lgkm, no barriers ----
#pragma unroll 1
    for (int g = g0; g < ngroups; g += gstride) {
        // 1) lane-contiguous row loads for g+1 (4 whole rows per instr)
        half8 rs[4], rd[4];
        rs[0] = *(const half8*)(xh + (size_t)sI.x * DF + goff);
        rs[1] = *(const half8*)(xh + (size_t)sI.y * DF + goff);
        rs[2] = *(const half8*)(xh + (size_t)sI.z * DF + goff);
        rs[3] = *(const half8*)(xh + (size_t)sI.w * DF + goff);
        rd[0] = *(const half8*)(xh + (size_t)dI.x * DF + goff);
        rd[1] = *(const half8*)(xh + (size_t)dI.y * DF + goff);
        rd[2] = *(const half8*)(xh + (size_t)dI.z * DF + goff);
        rd[3] = *(const half8*)(xh + (size_t)dI.w * DF + goff);

        // 2) ids for g + 2*gstride (VMEM dwordx4; stays in flight past diff)
        int4 sN, dN;
        {
            int g2 = g + 2 * gstride; if (g2 >= ngroups) g2 = g;
            const int eb = g2 * 64 + wv * 16;
            sN = *(const int4*)(idx + eb + idoff);
            dN = *(const int4*)(idx + n_edges + eb + idoff);
        }

        // 3) MFMA on LDS tile (group g): D[hid][edge] = W1^T * diff, acc=b1
        floatx4 acc[4];
#pragma unroll
        for (int mt = 0; mt < 4; ++mt)
#pragma unroll
            for (int r = 0; r < 4; ++r)
                acc[mt][r] = (float)b1h[mt][r];
#pragma unroll
        for (int kb = 0; kb < 4; ++kb) {
            const half8 bf = *(const half8*)(ldsw + rbase + kb * 32);
#pragma unroll
            for (int mt = 0; mt < 4; ++mt)
                acc[mt] = __builtin_amdgcn_mfma_f32_16x16x32_f16(wf[mt][kb], bf, acc[mt], 0, 0, 0);
        }

        // 4) epilogue: relu -> *W2 -> reduce over quads -> sigmoid -> store
        float part = 0.f;
#pragma unroll
        for (int mt = 0; mt < 4; ++mt)
#pragma unroll
            for (int r = 0; r < 4; ++r)
                part = fmaf(fmaxf(acc[mt][r], 0.f), (float)w2h[mt][r], part);
        part += __shfl_xor(part, 16, 64);
        part += __shfl_xor(part, 32, 64);
        if (L < 16) {
            const int e = g * 64 + wv * 16 + L;
            if (e < n_edges) out[e] = sigmoidf_(part + b2v);
        }

        // 5) diff (g+1) -> LDS (in-order DS: queues after this iter's reads)
#pragma unroll
        for (int p = 0; p < 4; ++p) {
            union { half8 h; uint4 u; } U;
            U.h = rs[p] - rd[p];
            U.u.x &= 0x7FFF7FFFu; U.u.y &= 0x7FFF7FFFu;
            U.u.z &= 0x7FFF7FFFu; U.u.w &= 0x7FFF7FFFu;
            *(half8*)(ldsw + wbase + p * AST) = U.h;
        }

        // 6) advance id pipeline
        sI = sN; dI = dN;
    }
}

// fallback / tail
__global__ void edge_naive(const float* __restrict__ x, const int* __restrict__ idx,
                           const float* __restrict__ W1, const float* __restrict__ b1,
                           const float* __restrict__ W2, const float* __restrict__ b2,
                           float* __restrict__ out, int n_edges, int start)
{
    int e = start + blockIdx.x * blockDim.x + threadIdx.x;
    if (e >= n_edges) return;
    int s = idx[e], d = idx[n_edges + e];
    float t = b2[0];
    for (int j = 0; j < HID; ++j) {
        float h = b1[j];
        for (int k = 0; k < DF; ++k)
            h = fmaf(fabsf(x[(size_t)s * DF + k] - x[(size_t)d * DF + k]), W1[(size_t)k * HID + j], h);
        t = fmaf(fmaxf(h, 0.f), W2[j], t);
    }
    out[e] = sigmoidf_(t);
}

extern "C" void kernel_launch(void* const* d_in, const int* in_sizes, int n_in,
                              void* d_out, int out_size, void* d_ws, size_t ws_size,
                              hipStream_t stream) {
    const float* x   = (const float*)d_in[0];
    const int*   idx = (const int*)d_in[1];
    const float* W1  = (const float*)d_in[2];
    const float* b1  = (const float*)d_in[3];
    const float* W2  = (const float*)d_in[4];
    const float* b2  = (const float*)d_in[5];
    float* out = (float*)d_out;

    const int n_edges = in_sizes[1] / 2;      // indices is [2, n_edges]
    const int n_x     = in_sizes[0];
    const int ngroups = n_edges / 64;
    const int rem     = n_edges - ngroups * 64;

    const size_t xh_bytes  = ((size_t)n_x * sizeof(_Float16) + 255) & ~(size_t)255;
    const size_t w1t_bytes = (size_t)DF * HID * sizeof(_Float16);
    const bool ok = (ws_size >= xh_bytes + w1t_bytes) && (n_x % 4 == 0) &&
                    (n_edges % 16 == 0);      // dwordx4 id loads need 16-alignment

    if (ok && ngroups > 0) {
        _Float16* xh  = (_Float16*)d_ws;
        _Float16* w1t = (_Float16*)((char*)d_ws + xh_bytes);
        const int n4 = n_x / 4;
        cvt_pre<<<(n4 + 255) / 256, 256, 0, stream>>>(x, W1, xh, w1t, n4);

        const int grid = ngroups < 768 ? ngroups : 768;   // 3 blocks/CU
        edge_mlp_v7<<<grid, 256, 0, stream>>>(xh, w1t, idx, b1, W2, b2,
                                              out, n_edges, ngroups, grid);
        if (rem > 0)
            edge_naive<<<(rem + 63) / 64, 64, 0, stream>>>(x, idx, W1, b1, W2, b2,
                                                           out, n_edges, ngroups * 64);
    } else {
        edge_naive<<<(n_edges + 63) / 64, 64, 0, stream>>>(x, idx, W1, b1, W2, b2,
                                                           out, n_edges, 0);
    }
}

// Round 8
// 97.078 us; speedup vs baseline: 1.2547x; 1.0089x over previous
//
#include <hip/hip_runtime.h>

// EdgeCompute v8: v7 + FORCED residency of W1^T fragments (anti-remat asm).
//   out = sigmoid( relu(|x[s]-x[d]| @ W1 + b1) @ W2 + b2 )
// N_EDGES=640000, D_FEAT=128, HID=64.
//
// Round-7 lesson: VGPR_Count=84 across v4..v7 proves the compiler never kept
// wf[4][4] (64 VGPRs of W1^T) resident -- it rematerialized all 16 scattered
// global_load_dwordx4 weight loads INSIDE every iteration (16 lines/instr ->
// ~256 lines/iter/wave TA load, vmcnt stalls before each MFMA group).
// Fix: empty `asm volatile("" : "+v"(frag))` after the one-time load makes
// the value opaque -> no remat, fragments stay in registers for the kernel's
// lifetime. Everything else identical to v7 (lane-contiguous row gather,
// per-wave LDS transpose, VMEM dwordx4 ids, DS-only lgkm, no barriers).

#define DF 128
#define HID 64
#define AST 136   // halfs per LDS diff row (272 B = 17*16B, 16B-aligned rows)

typedef _Float16 half8   __attribute__((ext_vector_type(8)));
typedef _Float16 half4_t __attribute__((ext_vector_type(4)));
typedef float    floatx4 __attribute__((ext_vector_type(4)));

__device__ __forceinline__ float sigmoidf_(float t) {
    return __builtin_amdgcn_rcpf(1.0f + __expf(-t));
}

// pre-pass: x -> f16 (2.56MB, L2-resident), W1 -> f16 transposed [hid][feat]
__global__ void cvt_pre(const float* __restrict__ x, const float* __restrict__ W1,
                        _Float16* __restrict__ xh, _Float16* __restrict__ w1t, int n4)
{
    const int i = blockIdx.x * blockDim.x + threadIdx.x;
    if (i < n4) {
        float4 v = ((const float4*)x)[i];
        half4_t h = { (_Float16)v.x, (_Float16)v.y, (_Float16)v.z, (_Float16)v.w };
        ((half4_t*)xh)[i] = h;
    }
    if (i < DF * HID) {                      // w1t[h*128+f] = W1[f*64+h]
        const int h = i >> 7, f = i & 127;
        w1t[i] = (_Float16)W1[f * HID + h];
    }
}

__global__ __launch_bounds__(256, 3) void edge_mlp_v8(
    const _Float16* __restrict__ xh, const _Float16* __restrict__ w1t,
    const int* __restrict__ idx,
    const float* __restrict__ b1, const float* __restrict__ W2,
    const float* __restrict__ b2,
    float* __restrict__ out, int n_edges, int ngroups, int gstride)
{
    // per-wave diff tile: [m=16 edges][k=128 (+8 pad)] f16
    __shared__ __attribute__((aligned(16))) _Float16 lds_d[4][16 * AST];

    const int tid = threadIdx.x;
    const int L   = tid & 63;
    const int r16 = L & 15;                 // frag-read: edge; gather: 16B chunk
    const int q   = L >> 4;                 // frag-read: quad; gather: row quartet
    const int wv  = tid >> 6;
    _Float16* const ldsw = &lds_d[wv][0];

    // ---- A fragments: W1^T [hid=mt*16+r16][feat=kb*32+q*8+j] (64 VGPRs) ----
    half8 wf[4][4];
#pragma unroll
    for (int mt = 0; mt < 4; ++mt)
#pragma unroll
        for (int kb = 0; kb < 4; ++kb)
            wf[mt][kb] = *(const half8*)(w1t + (size_t)(mt * 16 + r16) * DF + kb * 32 + q * 8);

    // ANTI-REMAT: make fragments opaque so the compiler cannot sink the
    // loads into the loop (the VGPR=84 signature of v4..v7).
#pragma unroll
    for (int mt = 0; mt < 4; ++mt)
#pragma unroll
        for (int kb = 0; kb < 4; ++kb)
            asm volatile("" : "+v"(wf[mt][kb]));

    // epilogue constants at hid = mt*16 + q*4 + r (f16-packed, 8 VGPRs)
    half4_t b1h[4], w2h[4];
#pragma unroll
    for (int mt = 0; mt < 4; ++mt)
#pragma unroll
        for (int r = 0; r < 4; ++r) {
            b1h[mt][r] = (_Float16)b1[mt * 16 + q * 4 + r];
            w2h[mt][r] = (_Float16)W2[mt * 16 + q * 4 + r];
        }
#pragma unroll
    for (int mt = 0; mt < 4; ++mt) {
        asm volatile("" : "+v"(b1h[mt]));
        asm volatile("" : "+v"(w2h[mt]));
    }
    const float b2v = b2[0];

    // per-lane fixed offsets
    const int goff  = r16 * 8;               // halfs into a row for the gather
    const int wbase = q * 4 * AST + r16 * 8; // LDS write vaddr; +p*AST imm
    const int rbase = r16 * AST + q * 8;     // LDS frag-read vaddr; +kb*32 imm
    const int idoff = q * 4;                 // this lane's 4 contiguous ids

    const int g0 = blockIdx.x;

    // ids for the group whose ROWS we issue next (VMEM dwordx4, 1 line/wave)
    int4 sI, dI;
    {
        const int eb = g0 * 64 + wv * 16;
        sI = *(const int4*)(idx + eb + idoff);
        dI = *(const int4*)(idx + n_edges + eb + idoff);
    }

    // ---- preamble: rows(g0) -> diff -> LDS ----
    {
        half8 rs[4], rd[4];
        rs[0] = *(const half8*)(xh + (size_t)sI.x * DF + goff);
        rs[1] = *(const half8*)(xh + (size_t)sI.y * DF + goff);
        rs[2] = *(const half8*)(xh + (size_t)sI.z * DF + goff);
        rs[3] = *(const half8*)(xh + (size_t)sI.w * DF + goff);
        rd[0] = *(const half8*)(xh + (size_t)dI.x * DF + goff);
        rd[1] = *(const half8*)(xh + (size_t)dI.y * DF + goff);
        rd[2] = *(const half8*)(xh + (size_t)dI.z * DF + goff);
        rd[3] = *(const half8*)(xh + (size_t)dI.w * DF + goff);
#pragma unroll
        for (int p = 0; p < 4; ++p) {
            union { half8 h; uint4 u; } U;
            U.h = rs[p] - rd[p];
            U.u.x &= 0x7FFF7FFFu; U.u.y &= 0x7FFF7FFFu;
            U.u.z &= 0x7FFF7FFFu; U.u.w &= 0x7FFF7FFFu;
            *(half8*)(ldsw + wbase + p * AST) = U.h;
        }
    }

    // ids for g0 + gstride
    {
        int g1 = g0 + gstride; if (g1 >= ngroups) g1 = g0;
        const int eb = g1 * 64 + wv * 16;
        sI = *(const int4*)(idx + eb + idoff);
        dI = *(const int4*)(idx + n_edges + eb + idoff);
    }

    // ---- main loop: DS-only lgkm, no barriers ----
#pragma unroll 1
    for (int g = g0; g < ngroups; g += gstride) {
        // 1) lane-contiguous row loads for g+1 (4 whole rows per instr)
        half8 rs[4], rd[4];
        rs[0] = *(const half8*)(xh + (size_t)sI.x * DF + goff);
        rs[1] = *(const half8*)(xh + (size_t)sI.y * DF + goff);
        rs[2] = *(const half8*)(xh + (size_t)sI.z * DF + goff);
        rs[3] = *(const half8*)(xh + (size_t)sI.w * DF + goff);
        rd[0] = *(const half8*)(xh + (size_t)dI.x * DF + goff);
        rd[1] = *(const half8*)(xh + (size_t)dI.y * DF + goff);
        rd[2] = *(const half8*)(xh + (size_t)dI.z * DF + goff);
        rd[3] = *(const half8*)(xh + (size_t)dI.w * DF + goff);

        // 2) ids for g + 2*gstride (VMEM dwordx4; stays in flight past diff)
        int4 sN, dN;
        {
            int g2 = g + 2 * gstride; if (g2 >= ngroups) g2 = g;
            const int eb = g2 * 64 + wv * 16;
            sN = *(const int4*)(idx + eb + idoff);
            dN = *(const int4*)(idx + n_edges + eb + idoff);
        }

        // 3) MFMA on LDS tile (group g): D[hid][edge] = W1^T * diff, acc=b1
        floatx4 acc[4];
#pragma unroll
        for (int mt = 0; mt < 4; ++mt)
#pragma unroll
            for (int r = 0; r < 4; ++r)
                acc[mt][r] = (float)b1h[mt][r];
#pragma unroll
        for (int kb = 0; kb < 4; ++kb) {
            const half8 bf = *(const half8*)(ldsw + rbase + kb * 32);
#pragma unroll
            for (int mt = 0; mt < 4; ++mt)
                acc[mt] = __builtin_amdgcn_mfma_f32_16x16x32_f16(wf[mt][kb], bf, acc[mt], 0, 0, 0);
        }

        // 4) epilogue: relu -> *W2 -> reduce over quads -> sigmoid -> store
        float part = 0.f;
#pragma unroll
        for (int mt = 0; mt < 4; ++mt)
#pragma unroll
            for (int r = 0; r < 4; ++r)
                part = fmaf(fmaxf(acc[mt][r], 0.f), (float)w2h[mt][r], part);
        part += __shfl_xor(part, 16, 64);
        part += __shfl_xor(part, 32, 64);
        if (L < 16) {
            const int e = g * 64 + wv * 16 + L;
            if (e < n_edges) out[e] = sigmoidf_(part + b2v);
        }

        // 5) diff (g+1) -> LDS (in-order DS: queues after this iter's reads)
#pragma unroll
        for (int p = 0; p < 4; ++p) {
            union { half8 h; uint4 u; } U;
            U.h = rs[p] - rd[p];
            U.u.x &= 0x7FFF7FFFu; U.u.y &= 0x7FFF7FFFu;
            U.u.z &= 0x7FFF7FFFu; U.u.w &= 0x7FFF7FFFu;
            *(half8*)(ldsw + wbase + p * AST) = U.h;
        }

        // 6) advance id pipeline
        sI = sN; dI = dN;
    }
}

// fallback / tail
__global__ void edge_naive(const float* __restrict__ x, const int* __restrict__ idx,
                           const float* __restrict__ W1, const float* __restrict__ b1,
                           const float* __restrict__ W2, const float* __restrict__ b2,
                           float* __restrict__ out, int n_edges, int start)
{
    int e = start + blockIdx.x * blockDim.x + threadIdx.x;
    if (e >= n_edges) return;
    int s = idx[e], d = idx[n_edges + e];
    float t = b2[0];
    for (int j = 0; j < HID; ++j) {
        float h = b1[j];
        for (int k = 0; k < DF; ++k)
            h = fmaf(fabsf(x[(size_t)s * DF + k] - x[(size_t)d * DF + k]), W1[(size_t)k * HID + j], h);
        t = fmaf(fmaxf(h, 0.f), W2[j], t);
    }
    out[e] = sigmoidf_(t);
}

extern "C" void kernel_launch(void* const* d_in, const int* in_sizes, int n_in,
                              void* d_out, int out_size, void* d_ws, size_t ws_size,
                              hipStream_t stream) {
    const float* x   = (const float*)d_in[0];
    const int*   idx = (const int*)d_in[1];
    const float* W1  = (const float*)d_in[2];
    const float* b1  = (const float*)d_in[3];
    const float* W2  = (const float*)d_in[4];
    const float* b2  = (const float*)d_in[5];
    float* out = (float*)d_out;

    const int n_edges = in_sizes[1] / 2;      // indices is [2, n_edges]
    const int n_x     = in_sizes[0];
    const int ngroups = n_edges / 64;
    const int rem     = n_edges - ngroups * 64;

    const size_t xh_bytes  = ((size_t)n_x * sizeof(_Float16) + 255) & ~(size_t)255;
    const size_t w1t_bytes = (size_t)DF * HID * sizeof(_Float16);
    const bool ok = (ws_size >= xh_bytes + w1t_bytes) && (n_x % 4 == 0) &&
                    (n_edges % 16 == 0);      // dwordx4 id loads need 16-alignment

    if (ok && ngroups > 0) {
        _Float16* xh  = (_Float16*)d_ws;
        _Float16* w1t = (_Float16*)((char*)d_ws + xh_bytes);
        const int n4 = n_x / 4;
        cvt_pre<<<(n4 + 255) / 256, 256, 0, stream>>>(x, W1, xh, w1t, n4);

        const int grid = ngroups < 768 ? ngroups : 768;   // 3 blocks/CU
        edge_mlp_v8<<<grid, 256, 0, stream>>>(xh, w1t, idx, b1, W2, b2,
                                              out, n_edges, ngroups, grid);
        if (rem > 0)
            edge_naive<<<(rem + 63) / 64, 64, 0, stream>>>(x, idx, W1, b1, W2, b2,
                                                           out, n_edges, ngroups * 64);
    } else {
        edge_naive<<<(n_edges + 63) / 64, 64, 0, stream>>>(x, idx, W1, b1, W2, b2,
                                                           out, n_edges, 0);
    }
}

// Round 9
// 94.912 us; speedup vs baseline: 1.2834x; 1.0228x over previous
//
#include <hip/hip_runtime.h>

// EdgeCompute v9: 64-edge wave tiles — 4x longer compute stretches per
// latency exposure.  out = sigmoid( relu(|x[s]-x[d]| @ W1 + b1) @ W2 + b2 )
// N_EDGES=640000, D_FEAT=128, HID=64.
//
// Rounds 6-8 lesson: with 16-edge wave tiles the per-iter MFMA stretch is
// ~78 cyc vs a ~600+ cyc gather->diff->LDS->MFMA chain repeated 13x/wave;
// no micro-fix changes that shape. v9: wave tile = 64 edges -> 64 MFMAs
// (~320 cyc) + batched gather (4 batches x 8 row-loads, 1.5-batch pipeline)
// + ids prefetched one full tile ahead; ~5 iterations per wave total.
// Kept: f16 x in d_ws (L2-resident), lane-contiguous row loads (4 full
// 256B rows per instr), per-wave LDS transpose (no barriers), W1^T in 64
// VGPRs, transposed MFMA D[hid][edge], 2-shfl epilogue, scalars + macros
// only (no spillable arrays).

#define DF 128
#define HID 64
#define AST 136   // halfs per LDS diff row (272 B = 17*16B)

typedef _Float16 half8   __attribute__((ext_vector_type(8)));
typedef _Float16 half4_t __attribute__((ext_vector_type(4)));
typedef float    floatx4 __attribute__((ext_vector_type(4)));

__device__ __forceinline__ float sigmoidf_(float t) {
    return __builtin_amdgcn_rcpf(1.0f + __expf(-t));
}

// pre-pass: x -> f16 (2.56MB, L2-resident), W1 -> f16 transposed [hid][feat]
__global__ void cvt_pre(const float* __restrict__ x, const float* __restrict__ W1,
                        _Float16* __restrict__ xh, _Float16* __restrict__ w1t, int n4)
{
    const int i = blockIdx.x * blockDim.x + threadIdx.x;
    if (i < n4) {
        float4 v = ((const float4*)x)[i];
        half4_t h = { (_Float16)v.x, (_Float16)v.y, (_Float16)v.z, (_Float16)v.w };
        ((half4_t*)xh)[i] = h;
    }
    if (i < DF * HID) {                      // w1t[h*128+f] = W1[f*64+h]
        const int h = i >> 7, f = i & 127;
        w1t[i] = (_Float16)W1[f * HID + h];
    }
}

#define ROW(idv) *(const half8*)(xh + (size_t)(idv) * DF + goff)

// issue 8 row loads (4 s-rows, 4 d-rows) for batch ids sIv/dIv
#define ISSUE(S, D, sIv, dIv)                                   \
    S##0 = ROW((sIv).x); S##1 = ROW((sIv).y);                   \
    S##2 = ROW((sIv).z); S##3 = ROW((sIv).w);                   \
    D##0 = ROW((dIv).x); D##1 = ROW((dIv).y);                   \
    D##2 = ROW((dIv).z); D##3 = ROW((dIv).w);

// |s - d| -> LDS rows (t*16 + q*4 + p), chunk r16
#define PROC(t, S, D) {                                                        \
    union { half8 h; uint4 u; } U0, U1, U2, U3;                                \
    U0.h = S##0 - D##0; U1.h = S##1 - D##1;                                    \
    U2.h = S##2 - D##2; U3.h = S##3 - D##3;                                    \
    U0.u.x &= 0x7FFF7FFFu; U0.u.y &= 0x7FFF7FFFu;                              \
    U0.u.z &= 0x7FFF7FFFu; U0.u.w &= 0x7FFF7FFFu;                              \
    U1.u.x &= 0x7FFF7FFFu; U1.u.y &= 0x7FFF7FFFu;                              \
    U1.u.z &= 0x7FFF7FFFu; U1.u.w &= 0x7FFF7FFFu;                              \
    U2.u.x &= 0x7FFF7FFFu; U2.u.y &= 0x7FFF7FFFu;                              \
    U2.u.z &= 0x7FFF7FFFu; U2.u.w &= 0x7FFF7FFFu;                              \
    U3.u.x &= 0x7FFF7FFFu; U3.u.y &= 0x7FFF7FFFu;                              \
    U3.u.z &= 0x7FFF7FFFu; U3.u.w &= 0x7FFF7FFFu;                              \
    *(half8*)(ldsw + ((t) * 16 + q * 4 + 0) * AST + goff) = U0.h;              \
    *(half8*)(ldsw + ((t) * 16 + q * 4 + 1) * AST + goff) = U1.h;              \
    *(half8*)(ldsw + ((t) * 16 + q * 4 + 2) * AST + goff) = U2.h;              \
    *(half8*)(ldsw + ((t) * 16 + q * 4 + 3) * AST + goff) = U3.h; }

__global__ __launch_bounds__(256, 2) void edge_mlp_v9(
    const _Float16* __restrict__ xh, const _Float16* __restrict__ w1t,
    const int* __restrict__ idx,
    const float* __restrict__ b1, const float* __restrict__ W2,
    const float* __restrict__ b2,
    float* __restrict__ out, int n_edges, int ngroups, int gstride)
{
    // per-wave diff tile: [64 edges][128 k (+8 pad)] f16 = 17.4KB x 4 waves
    __shared__ __attribute__((aligned(16))) _Float16 lds_d[4][64 * AST];

    const int tid = threadIdx.x;
    const int L   = tid & 63;
    const int r16 = L & 15;                 // frag-read: edge; gather: 16B chunk
    const int q   = L >> 4;                 // frag-read: quad; gather: row-in-quartet
    const int wv  = tid >> 6;
    _Float16* const ldsw = &lds_d[wv][0];

    // ---- A fragments: W1^T [hid=mt*16+r16][k=kb*32+q*8+j] (64 VGPRs) ----
    half8 wf[4][4];
#pragma unroll
    for (int mt = 0; mt < 4; ++mt)
#pragma unroll
        for (int kb = 0; kb < 4; ++kb)
            wf[mt][kb] = *(const half8*)(w1t + (size_t)(mt * 16 + r16) * DF + kb * 32 + q * 8);
#pragma unroll
    for (int mt = 0; mt < 4; ++mt)
#pragma unroll
        for (int kb = 0; kb < 4; ++kb)
            asm volatile("" : "+v"(wf[mt][kb]));

    // epilogue constants at hid = mt*16 + q*4 + r (f16-packed, 8 VGPRs)
    half4_t b1h[4], w2h[4];
#pragma unroll
    for (int mt = 0; mt < 4; ++mt)
#pragma unroll
        for (int r = 0; r < 4; ++r) {
            b1h[mt][r] = (_Float16)b1[mt * 16 + q * 4 + r];
            w2h[mt][r] = (_Float16)W2[mt * 16 + q * 4 + r];
        }
    const float b2v = b2[0];

    const int goff = r16 * 8;    // 16B chunk offset, shared by gather + LDS write
    const int idof = q * 4;      // this lane's 4 contiguous ids per 16-edge batch

    const int g0 = blockIdx.x;

    // ids for tile g0 (8 x int4; one 64B line per load)
    int4 sI0, sI1, sI2, sI3, dI0, dI1, dI2, dI3;
    {
        const int eb = g0 * 256 + wv * 64;
        sI0 = *(const int4*)(idx + eb +  0 + idof);
        sI1 = *(const int4*)(idx + eb + 16 + idof);
        sI2 = *(const int4*)(idx + eb + 32 + idof);
        sI3 = *(const int4*)(idx + eb + 48 + idof);
        dI0 = *(const int4*)(idx + n_edges + eb +  0 + idof);
        dI1 = *(const int4*)(idx + n_edges + eb + 16 + idof);
        dI2 = *(const int4*)(idx + n_edges + eb + 32 + idof);
        dI3 = *(const int4*)(idx + n_edges + eb + 48 + idof);
    }

#pragma unroll 1
    for (int g = g0; g < ngroups; g += gstride) {
        half8 sa0, sa1, sa2, sa3, da0, da1, da2, da3;   // buffer A
        half8 sb0, sb1, sb2, sb3, db0, db1, db2, db3;   // buffer B

        // batched gather: 1.5 batches in flight
        ISSUE(sa, da, sI0, dI0);
        ISSUE(sb, db, sI1, dI1);
        PROC(0, sa, da);
        ISSUE(sa, da, sI2, dI2);
        PROC(1, sb, db);
        ISSUE(sb, db, sI3, dI3);
        PROC(2, sa, da);

        // prefetch ids for the NEXT tile (arrive during MFMA/epilogue)
        int4 sN0, sN1, sN2, sN3, dN0, dN1, dN2, dN3;
        {
            int gn = g + gstride; if (gn >= ngroups) gn = g;
            const int ebn = gn * 256 + wv * 64;
            sN0 = *(const int4*)(idx + ebn +  0 + idof);
            sN1 = *(const int4*)(idx + ebn + 16 + idof);
            sN2 = *(const int4*)(idx + ebn + 32 + idof);
            sN3 = *(const int4*)(idx + ebn + 48 + idof);
            dN0 = *(const int4*)(idx + n_edges + ebn +  0 + idof);
            dN1 = *(const int4*)(idx + n_edges + ebn + 16 + idof);
            dN2 = *(const int4*)(idx + n_edges + ebn + 32 + idof);
            dN3 = *(const int4*)(idx + n_edges + ebn + 48 + idof);
        }

        PROC(3, sb, db);

        // ---- MFMA: D[hid 64][edge 64] = W1^T * diff ----
        floatx4 acc[4][4];                  // acc[mt][et]
#pragma unroll
        for (int mt = 0; mt < 4; ++mt)
#pragma unroll
            for (int et = 0; et < 4; ++et)
                acc[mt][et] = (floatx4){0.f, 0.f, 0.f, 0.f};
#pragma unroll
        for (int kb = 0; kb < 4; ++kb) {
#pragma unroll
            for (int et = 0; et < 4; ++et) {
                const half8 bf = *(const half8*)(ldsw + (et * 16 + r16) * AST + kb * 32 + q * 8);
                acc[0][et] = __builtin_amdgcn_mfma_f32_16x16x32_f16(wf[0][kb], bf, acc[0][et], 0, 0, 0);
                acc[1][et] = __builtin_amdgcn_mfma_f32_16x16x32_f16(wf[1][kb], bf, acc[1][et], 0, 0, 0);
                acc[2][et] = __builtin_amdgcn_mfma_f32_16x16x32_f16(wf[2][kb], bf, acc[2][et], 0, 0, 0);
                acc[3][et] = __builtin_amdgcn_mfma_f32_16x16x32_f16(wf[3][kb], bf, acc[3][et], 0, 0, 0);
            }
        }

        // advance id pipeline (row bufs dead; regs free)
        sI0 = sN0; sI1 = sN1; sI2 = sN2; sI3 = sN3;
        dI0 = dN0; dI1 = dN1; dI2 = dN2; dI3 = dN3;

        // ---- epilogue: relu -> *W2 -> reduce over quads -> sigmoid ----
#pragma unroll
        for (int et = 0; et < 4; ++et) {
            float part = 0.f;
#pragma unroll
            for (int mt = 0; mt < 4; ++mt)
#pragma unroll
                for (int r = 0; r < 4; ++r)
                    part = fmaf(fmaxf(acc[mt][et][r] + (float)b1h[mt][r], 0.f),
                                (float)w2h[mt][r], part);
            part += __shfl_xor(part, 16, 64);
            part += __shfl_xor(part, 32, 64);
            if (L < 16)
                out[g * 256 + wv * 64 + et * 16 + L] = sigmoidf_(part + b2v);
        }
    }
}

// fallback / tail
__global__ void edge_naive(const float* __restrict__ x, const int* __restrict__ idx,
                           const float* __restrict__ W1, const float* __restrict__ b1,
                           const float* __restrict__ W2, const float* __restrict__ b2,
                           float* __restrict__ out, int n_edges, int start)
{
    int e = start + blockIdx.x * blockDim.x + threadIdx.x;
    if (e >= n_edges) return;
    int s = idx[e], d = idx[n_edges + e];
    float t = b2[0];
    for (int j = 0; j < HID; ++j) {
        float h = b1[j];
        for (int k = 0; k < DF; ++k)
            h = fmaf(fabsf(x[(size_t)s * DF + k] - x[(size_t)d * DF + k]), W1[(size_t)k * HID + j], h);
        t = fmaf(fmaxf(h, 0.f), W2[j], t);
    }
    out[e] = sigmoidf_(t);
}

extern "C" void kernel_launch(void* const* d_in, const int* in_sizes, int n_in,
                              void* d_out, int out_size, void* d_ws, size_t ws_size,
                              hipStream_t stream) {
    const float* x   = (const float*)d_in[0];
    const int*   idx = (const int*)d_in[1];
    const float* W1  = (const float*)d_in[2];
    const float* b1  = (const float*)d_in[3];
    const float* W2  = (const float*)d_in[4];
    const float* b2  = (const float*)d_in[5];
    float* out = (float*)d_out;

    const int n_edges = in_sizes[1] / 2;      // indices is [2, n_edges]
    const int n_x     = in_sizes[0];
    const int ngroups = n_edges / 256;        // 256 edges per block-tile
    const int rem     = n_edges - ngroups * 256;

    const size_t xh_bytes  = ((size_t)n_x * sizeof(_Float16) + 255) & ~(size_t)255;
    const size_t w1t_bytes = (size_t)DF * HID * sizeof(_Float16);
    const bool ok = (ws_size >= xh_bytes + w1t_bytes) && (n_x % 4 == 0);

    if (ok && ngroups > 0) {
        _Float16* xh  = (_Float16*)d_ws;
        _Float16* w1t = (_Float16*)((char*)d_ws + xh_bytes);
        const int n4 = n_x / 4;
        cvt_pre<<<(n4 + 255) / 256, 256, 0, stream>>>(x, W1, xh, w1t, n4);

        const int grid = ngroups < 512 ? ngroups : 512;   // 2 blocks/CU
        edge_mlp_v9<<<grid, 256, 0, stream>>>(xh, w1t, idx, b1, W2, b2,
                                              out, n_edges, ngroups, grid);
        if (rem > 0)
            edge_naive<<<(rem + 63) / 64, 64, 0, stream>>>(x, idx, W1, b1, W2, b2,
                                                           out, n_edges, ngroups * 256);
    } else {
        edge_naive<<<(n_edges + 63) / 64, 64, 0, stream>>>(x, idx, W1, b1, W2, b2,
                                                           out, n_edges, 0);
    }
}